// Round 7
// baseline (285.730 us; speedup 1.0000x reference)
//
#include <hip/hip_runtime.h>
#include <stdint.h>

// out[ch][s] = sum_{v: sp[v]==s} x[ch][ht[v]] * w[v],  ch in [0,128)
//
// R1: atomic scatter wrote 768 MB -> bin by sphere (601us).
// R2: accum f32 gather bound -> bf16 xT (516us).
// R3: scatter 8B-random writes: 95MB amp + per-vote cursor atomics (115us).
// R4 FAILED (1532us): accum latency-bound (dependent global chains).
// R5 (409us): 1024-bucket sort + LDS-staged accum.
// R6 FAILED (absmax 17): epilogue cross-half LDS combine was an intra-wave race.
// R7 (317us): halves combined in REGISTERS via __shfl_xor(.,32).
// R8 NEUTRAL (315us): quarter-wave gather -> null => not issue-bound.
// R9 NEUTRAL (319us): fused transpose+reorder; diagnostic (latency-bound).
// R10 NULL (320us): cursor line-padding -> atomics exonerated.
// R11 WIN (299us): CHUNK=8192 full-line runs; write-amp gone (112->87MB).
// R12 MIXED (303us): block-major records (no atomics/binsearch/spill in
//     reorder dump) but accum staging serialized on 184/512 threads.
// R13 WIN (281us): accum MLP fix (clamped unconditional gather + unroll 2,
//     all-thread binsearch staging, per-bin 8-reg acc). Both kernels now
//     below the 79.5us harness fill; harness ~135-165us of dur, kernel
//     slack ~30-45us total vs floors.
// R14: residual-slack probes: accum unroll 4 (16 gathers in flight;
//     pre-commit: positive=still latency-limited, null=at traffic floor);
//     transpose 2x64 tiles/block (2048 blocks, less dispatch/tail).

#define S_BINS   32768
#define NBUCKET  1024        // coarse buckets = s >> 5
#define BINS     32          // fine bins per bucket
#define CAP      2048        // accum LDS capacity per bucket (mean 1465, +15 sigma)
#define CHUNK    8192        // votes per reorder block
#define MAXRB    192         // max reorder blocks supported (nrb = 184)
#define HT_BITS  18          // HW = 512*512 = 2^18

__device__ __forceinline__ unsigned bf16_rne(float f) {
    unsigned u = __float_as_uint(f);
    return (u + 0x7FFFu + ((u >> 16) & 1u)) >> 16;   // round-nearest-even
}

// Fused: blockIdx < nrb  -> reorder role: bucket-sort CHUNK votes in LDS,
//                           dump sorted chunk SEQUENTIALLY to records[blk*CHUNK],
//                           write 1024 bucket-end offsets to blkcur[blk][.].
//                           record: x = ht | s_local<<18, y = w bits.
//        blockIdx >= nrb -> transpose role: 2 tiles of 64 ht-cells:
//                           x [128][HW] f32 -> xTb [HW][64] u32;
//                           word cp = bf16(ch=cp) | bf16(ch=cp+64)<<16.
// Roles are data-independent; fusing overlaps HBM-bound transpose with
// latency-bound reorder. Shared ~68 KB LDS (union of both layouts).
__global__ __launch_bounds__(512) void fused_tr_kernel(
    const float* __restrict__ x, uint32_t* __restrict__ xTb, int HW,
    const int* __restrict__ ht, const int* __restrict__ sp,
    const float* __restrict__ w,
    uint2* __restrict__ records, int* __restrict__ blkcur,
    int V, int nrb) {
    __shared__ __align__(16) char smem[69696];         // 68.1 KB -> 2 blk/CU
    const int t = threadIdx.x;                         // 512
    if ((int)blockIdx.x < nrb) {
        // ---------------- reorder role ----------------
        uint2* rec  = (uint2*)smem;                    // [8192] 64 KB
        int*   hcur = (int*)(smem + 65536);            // [1024]  4 KB (hist->cur)
        int*   wsum = (int*)(smem + 69632);            // [8]    32 B
        const int blk = blockIdx.x;
        const int lane = t & 63, wv = t >> 6;          // 8 waves
        const int base = blk * CHUNK, end = min(V, base + CHUNK), n = end - base;
        hcur[2 * t] = 0; hcur[2 * t + 1] = 0;
        __syncthreads();
        for (int v = base + t; v < end; v += 512) atomicAdd(&hcur[sp[v] >> 5], 1);
        __syncthreads();
        // exclusive scan of 1024 hist entries: shfl wave-scan, 2 barriers.
        // thread t owns buckets {2t,2t+1}; each thread touches only its own
        // hcur entries between the barriers (safe in-place reuse).
        const int l0 = hcur[2 * t], l1 = hcur[2 * t + 1];
        const int tot = l0 + l1;
        int sc = tot;                                   // inclusive within wave
#pragma unroll
        for (int off = 1; off < 64; off <<= 1) {
            const int up = __shfl_up(sc, off);
            if (lane >= off) sc += up;
        }
        if (lane == 63) wsum[wv] = sc;                  // wave totals
        __syncthreads();
        if (wv == 0 && lane < 8) {                      // exclusive scan of 8
            const int v0 = wsum[lane];
            int s = v0;
#pragma unroll
            for (int off = 1; off < 8; off <<= 1) {
                const int up = __shfl_up(s, off);
                if (lane >= off) s += up;
            }
            wsum[lane] = s - v0;
        }
        __syncthreads();
        const int run = wsum[wv] + (sc - tot);          // global exclusive prefix
        hcur[2 * t]     = run;
        hcur[2 * t + 1] = run + l0;
        __syncthreads();
        for (int v = base + t; v < end; v += 512) {     // place sorted in LDS
            const int s = sp[v];
            const int b = s >> 5, sl = s & 31;
            const int pos = atomicAdd(&hcur[b], 1);
            rec[pos] = make_uint2((unsigned)ht[v] | ((unsigned)sl << HT_BITS),
                                  __float_as_uint(w[v]));
        }
        __syncthreads();
        // dump: fully sequential, coalesced; hcur[b] is now bucket b's END.
        for (int i = t; i < n; i += 512)
            records[(size_t)blk * CHUNK + i] = rec[i];
        blkcur[(size_t)blk * NBUCKET + 2 * t]     = hcur[2 * t];
        blkcur[(size_t)blk * NBUCKET + 2 * t + 1] = hcur[2 * t + 1];
    } else {
        // ---------------- transpose role: 2 tiles of 64 cells ----------------
        float* tile = (float*)smem;                     // [64][129] 33 KB
        const int tile0 = ((int)blockIdx.x - nrb) * 128;
#pragma unroll 1
        for (int half = 0; half < 2; ++half) {
            const int ht0 = tile0 + half * 64;
            for (int e = t; e < 128 * 16; e += 512) {   // float4 loads
                const int ch = e >> 4, hq = e & 15;
                const float4 v = *(const float4*)(x + (size_t)ch * HW + ht0 + 4 * hq);
                const int a = 4 * hq;
                tile[(a + 0) * 129 + ch] = v.x;
                tile[(a + 1) * 129 + ch] = v.y;
                tile[(a + 2) * 129 + ch] = v.z;
                tile[(a + 3) * 129 + ch] = v.w;
            }
            __syncthreads();
            for (int e = t; e < 64 * 32; e += 512) {    // uint2 stores
                const int hl = e >> 5, cp = (e & 31) * 2;
                const unsigned lo0 = bf16_rne(tile[hl * 129 + cp]);
                const unsigned hi0 = bf16_rne(tile[hl * 129 + cp + 64]);
                const unsigned lo1 = bf16_rne(tile[hl * 129 + cp + 1]);
                const unsigned hi1 = bf16_rne(tile[hl * 129 + cp + 65]);
                *(uint2*)(xTb + (size_t)(ht0 + hl) * 64 + cp) =
                    make_uint2(lo0 | (hi0 << 16), lo1 | (hi1 << 16));
            }
            __syncthreads();                            // before tile reuse
        }
    }
}

// One block per bucket, 8 waves x 64 lanes. Stage: all 512 threads copy
// record i (segment found by 8-step LDS binsearch over segpos; consecutive
// i -> same segment -> coalesced reads), then fine-sort into 32 bins.
// Gather: wave owns 4 bins, processed one at a time with 8 register
// accumulators; QUARTER-WAVE processes one vote (lane ql loads dwordx4 =
// channels {4ql..4ql+3, 4ql+64..4ql+67}); loop is clamp-padded
// (kc=min(kk,s1-1), wt=0 pad) so loads are unconditional -> unroll 4 gives
// 16 gathers in flight. Quarters combined via shfl_xor(16)+(32); lanes 0..15
// write the bin's epi row right after its reduce (epi rows wave-disjoint;
// rawbuf is dead after fine-sort).
__global__ __launch_bounds__(512) void accum_kernel(
    const uint32_t* __restrict__ xTb, const uint2* __restrict__ records,
    const int* __restrict__ blkcur, int nrb, float* __restrict__ out) {
    __shared__ uint2 sorted[CAP];                        // 16 KB
    __shared__ __align__(16) char rawbuf[BINS * 129 * 4];// 16.5 KB raw/epilogue
    __shared__ int hist[BINS], off[BINS + 1], cur[BINS];
    __shared__ int segcnt[MAXRB], segpos[MAXRB], segs0[MAXRB];
    __shared__ int ntot;
    uint2* raw = (uint2*)rawbuf;
    float* epi = (float*)rawbuf;                         // [32][129] after sort
    const uint4* xTb4 = (const uint4*)xTb;               // [HW][16] uint4 rows
    const int bkt = blockIdx.x, t = threadIdx.x;
    const int lane = t & 63, wv = t >> 6;                // 8 waves
    const int q = lane >> 4, ql = lane & 15;             // quarter-wave id/lane

    if (t < BINS) hist[t] = 0;
    // segment boundaries for this bucket in each block's sorted chunk
    if (t < nrb) {
        const int e1 = blkcur[(size_t)t * NBUCKET + bkt];
        const int s0 = (bkt == 0) ? 0 : blkcur[(size_t)t * NBUCKET + bkt - 1];
        segcnt[t] = e1 - s0;
        segs0[t]  = s0;
    }
    __syncthreads();
    if (wv == 0) {                                       // scan nrb counts
        int carry = 0;
        for (int b0 = 0; b0 < nrb; b0 += 64) {
            const int idx = b0 + lane;
            const int c = (idx < nrb) ? segcnt[idx] : 0;
            int sc = c;
#pragma unroll
            for (int off2 = 1; off2 < 64; off2 <<= 1) {
                const int up = __shfl_up(sc, off2);
                if (lane >= off2) sc += up;
            }
            if (idx < nrb) segpos[idx] = carry + sc - c; // exclusive
            carry += __shfl(sc, 63);
        }
        if (lane == 0) ntot = carry;
    }
    __syncthreads();
    const int n = min(ntot, CAP);                        // CAP = +15 sigma guard
    // all-thread staging: 8-step binsearch for segment of record i
    for (int i = t; i < n; i += 512) {
        int lo = 0, hi = nrb - 1;
#pragma unroll
        for (int it = 0; it < 8; ++it) {                 // 2^8 >= MAXRB
            const int mid = (lo + hi + 1) >> 1;
            if (segpos[mid] <= i) lo = mid; else hi = mid - 1;
        }
        const uint2 r = records[(size_t)lo * CHUNK + segs0[lo] + (i - segpos[lo])];
        raw[i] = r;
        atomicAdd(&hist[(r.x >> HT_BITS) & 31], 1);
    }
    __syncthreads();
    if (t == 0) {                                        // tiny 32-entry scan
        int run = 0;
        for (int j = 0; j < BINS; ++j) { off[j] = run; cur[j] = run; run += hist[j]; }
        off[BINS] = run;
    }
    __syncthreads();
    for (int i = t; i < n; i += 512) {                   // place fine-sorted
        const uint2 r = raw[i];
        const int pos = atomicAdd(&cur[(r.x >> HT_BITS) & 31], 1);
        sorted[pos] = r;
    }
    __syncthreads();                                     // rawbuf now dead -> epi
#pragma unroll 1
    for (int bb = 0; bb < 4; ++bb) {                     // wave-uniform control
        const int f = wv * 4 + bb;
        const int s0f = off[f], s1f = off[f + 1];
        float a0 = 0.f, a1 = 0.f, a2 = 0.f, a3 = 0.f;
        float a4 = 0.f, a5 = 0.f, a6 = 0.f, a7 = 0.f;
#pragma unroll 4
        for (int k = s0f; k < s1f; k += 16) {            // 4 votes/wave/iter
#pragma unroll
            for (int u = 0; u < 4; ++u) {
                const int kk = k + 4 * u + q;
                const int kc = min(kk, s1f - 1);         // clamp: loads uncond.
                const uint2 r = sorted[kc];              // 4-addr LDS broadcast
                const uint4 g = xTb4[(size_t)(r.x & 0x3FFFF) * 16 + ql];
                const float wt = (kk < s1f) ? __uint_as_float(r.y) : 0.f;
                a0 += __uint_as_float(g.x << 16)          * wt;
                a1 += __uint_as_float(g.x & 0xFFFF0000u)  * wt;
                a2 += __uint_as_float(g.y << 16)          * wt;
                a3 += __uint_as_float(g.y & 0xFFFF0000u)  * wt;
                a4 += __uint_as_float(g.z << 16)          * wt;
                a5 += __uint_as_float(g.z & 0xFFFF0000u)  * wt;
                a6 += __uint_as_float(g.w << 16)          * wt;
                a7 += __uint_as_float(g.w & 0xFFFF0000u)  * wt;
            }
        }
        // combine quarter-waves in registers: lane^16 then lane^32 (race-free)
        a0 += __shfl_xor(a0, 16); a0 += __shfl_xor(a0, 32);
        a1 += __shfl_xor(a1, 16); a1 += __shfl_xor(a1, 32);
        a2 += __shfl_xor(a2, 16); a2 += __shfl_xor(a2, 32);
        a3 += __shfl_xor(a3, 16); a3 += __shfl_xor(a3, 32);
        a4 += __shfl_xor(a4, 16); a4 += __shfl_xor(a4, 32);
        a5 += __shfl_xor(a5, 16); a5 += __shfl_xor(a5, 32);
        a6 += __shfl_xor(a6, 16); a6 += __shfl_xor(a6, 32);
        a7 += __shfl_xor(a7, 16); a7 += __shfl_xor(a7, 32);
        // write this bin's epi row now (rows are wave-disjoint: f = wv*4+bb)
        if (lane < 16) {
            epi[f * 129 + 4 * ql]      = a0;
            epi[f * 129 + 4 * ql + 64] = a1;
            epi[f * 129 + 4 * ql + 1]  = a2;
            epi[f * 129 + 4 * ql + 65] = a3;
            epi[f * 129 + 4 * ql + 2]  = a4;
            epi[f * 129 + 4 * ql + 66] = a5;
            epi[f * 129 + 4 * ql + 3]  = a6;
            epi[f * 129 + 4 * ql + 67] = a7;
        }
    }
    __syncthreads();
    for (int i = t; i < 128 * BINS; i += 512) {
        const int ch = i >> 5, bin = i & 31;
        out[(size_t)ch * S_BINS + bkt * BINS + bin] = epi[bin * 129 + ch];
    }
}

// ---- fallback (direct atomic, any shape) ----
__global__ void direct_kernel(const float* __restrict__ x,
                              const int* __restrict__ ht_idx,
                              const int* __restrict__ sp_idx,
                              const float* __restrict__ weight,
                              float* __restrict__ out, int V, int HW, int S,
                              int CH) {
    const int v = blockIdx.x * 2 + (threadIdx.x >> 7);
    if (v >= V) return;
    const int ch = threadIdx.x & 127;
    if (ch >= CH) return;
    atomicAdd(&out[(size_t)ch * S + sp_idx[v]],
              x[(size_t)ch * HW + ht_idx[v]] * weight[v]);
}

extern "C" void kernel_launch(void* const* d_in, const int* in_sizes, int n_in,
                              void* d_out, int out_size, void* d_ws, size_t ws_size,
                              hipStream_t stream) {
    const float* x  = (const float*)d_in[0];
    const int*   ht = (const int*)d_in[1];
    const int*   sp = (const int*)d_in[2];
    const float* w  = (const float*)d_in[3];
    float* out = (float*)d_out;

    const int HW = 512 * 512;
    const int CH = in_sizes[0] / HW;          // 128
    const int S  = out_size / CH;             // 32768
    const int V  = in_sizes[1];               // 1.5M
    const int nrb = (V + CHUNK - 1) / CHUNK;  // 184 reorder-role blocks
    const int ntb = HW / 128;                 // 2048 transpose-role blocks

    const size_t xTb_bytes = (size_t)CH * HW * sizeof(uint16_t);      // 64 MB
    const size_t rec_bytes = (size_t)MAXRB * CHUNK * sizeof(uint2);   // 12.6 MB
    const size_t cur_bytes = (size_t)MAXRB * NBUCKET * sizeof(int);   // 0.79 MB
    const size_t need = xTb_bytes + rec_bytes + cur_bytes;

    if (CH == 128 && S == S_BINS && HW == (1 << HT_BITS) && nrb <= MAXRB &&
        ws_size >= need) {
        char* p = (char*)d_ws;
        uint32_t* xTb  = (uint32_t*)p;  p += xTb_bytes;
        uint2* records = (uint2*)p;     p += rec_bytes;
        int* blkcur    = (int*)p;

        fused_tr_kernel<<<nrb + ntb, 512, 0, stream>>>(
            x, xTb, HW, ht, sp, w, records, blkcur, V, nrb);
        accum_kernel<<<NBUCKET, 512, 0, stream>>>(xTb, records, blkcur, nrb,
                                                  out);
    } else {
        hipMemsetAsync(out, 0, (size_t)out_size * sizeof(float), stream);
        direct_kernel<<<(V + 1) / 2, 256, 0, stream>>>(x, ht, sp, w, out, V, HW,
                                                       S, CH);
    }
}

// Round 8
// 280.674 us; speedup vs baseline: 1.0180x; 1.0180x over previous
//
#include <hip/hip_runtime.h>
#include <stdint.h>

// out[ch][s] = sum_{v: sp[v]==s} x[ch][ht[v]] * w[v],  ch in [0,128)
//
// R1: atomic scatter wrote 768 MB -> bin by sphere (601us).
// R2: accum f32 gather bound -> bf16 xT (516us).
// R3: scatter 8B-random writes: 95MB amp + per-vote cursor atomics (115us).
// R4 FAILED (1532us): accum latency-bound (dependent global chains).
// R5 (409us): 1024-bucket sort + LDS-staged accum.
// R6 FAILED (absmax 17): epilogue cross-half LDS combine was an intra-wave race.
// R7 (317us): halves combined in REGISTERS via __shfl_xor(.,32).
// R8 NEUTRAL (315us): quarter-wave gather -> null => not issue-bound.
// R9 NEUTRAL (319us): fused transpose+reorder; diagnostic (latency-bound).
// R10 NULL (320us): cursor line-padding -> atomics exonerated.
// R11 WIN (299us): CHUNK=8192 full-line runs; write-amp gone (112->87MB).
// R12 MIXED (303us): block-major records; accum staging serialized.
// R13 WIN (281us): accum MLP fix (clamped unconditional gather + unroll 2,
//     all-thread binsearch staging, per-bin 8-reg acc). Both kernels below
//     the 79.5us harness fill.
// R14 REGRESS (286us): unroll 4 null (pre-commit: accum at traffic floor);
//     2-tile transpose slight loss. Both reverted.
// R15: exact R13 config + nontemporal stores for `out` epilogue (write-once,
//     never re-read; keep L2 lines for the gather table). fp8 table rejected
//     (error x32 vs bf16 -> predicted absmax ~4); channel-split rejected
//     (8 XCD x 4MB x 16g = 512MB HBM fills > current 197MB FETCH).
//     Remaining structure: ~170us harness + ~30-35 transpose/reorder (stream
//     BW floor) + ~65-70 accum (random-64B HBM/LLC roofline).

#define S_BINS   32768
#define NBUCKET  1024        // coarse buckets = s >> 5
#define BINS     32          // fine bins per bucket
#define CAP      2048        // accum LDS capacity per bucket (mean 1465, +15 sigma)
#define CHUNK    8192        // votes per reorder block
#define MAXRB    192         // max reorder blocks supported (nrb = 184)
#define HT_BITS  18          // HW = 512*512 = 2^18

__device__ __forceinline__ unsigned bf16_rne(float f) {
    unsigned u = __float_as_uint(f);
    return (u + 0x7FFFu + ((u >> 16) & 1u)) >> 16;   // round-nearest-even
}

// Fused: blockIdx < nrb  -> reorder role: bucket-sort CHUNK votes in LDS,
//                           dump sorted chunk SEQUENTIALLY to records[blk*CHUNK],
//                           write 1024 bucket-end offsets to blkcur[blk][.].
//                           record: x = ht | s_local<<18, y = w bits.
//        blockIdx >= nrb -> transpose role: x [128][HW] f32 -> xTb [HW][64]
//                           u32; word cp = bf16(ch=cp) | bf16(ch=cp+64)<<16.
// Roles are data-independent; fusing overlaps HBM-bound transpose with
// latency-bound reorder. Shared ~68 KB LDS (union of both layouts).
__global__ __launch_bounds__(512) void fused_tr_kernel(
    const float* __restrict__ x, uint32_t* __restrict__ xTb, int HW,
    const int* __restrict__ ht, const int* __restrict__ sp,
    const float* __restrict__ w,
    uint2* __restrict__ records, int* __restrict__ blkcur,
    int V, int nrb) {
    __shared__ __align__(16) char smem[69696];         // 68.1 KB -> 2 blk/CU
    const int t = threadIdx.x;                         // 512
    if ((int)blockIdx.x < nrb) {
        // ---------------- reorder role ----------------
        uint2* rec  = (uint2*)smem;                    // [8192] 64 KB
        int*   hcur = (int*)(smem + 65536);            // [1024]  4 KB (hist->cur)
        int*   wsum = (int*)(smem + 69632);            // [8]    32 B
        const int blk = blockIdx.x;
        const int lane = t & 63, wv = t >> 6;          // 8 waves
        const int base = blk * CHUNK, end = min(V, base + CHUNK), n = end - base;
        hcur[2 * t] = 0; hcur[2 * t + 1] = 0;
        __syncthreads();
        for (int v = base + t; v < end; v += 512) atomicAdd(&hcur[sp[v] >> 5], 1);
        __syncthreads();
        // exclusive scan of 1024 hist entries: shfl wave-scan, 2 barriers.
        // thread t owns buckets {2t,2t+1}; each thread touches only its own
        // hcur entries between the barriers (safe in-place reuse).
        const int l0 = hcur[2 * t], l1 = hcur[2 * t + 1];
        const int tot = l0 + l1;
        int sc = tot;                                   // inclusive within wave
#pragma unroll
        for (int off = 1; off < 64; off <<= 1) {
            const int up = __shfl_up(sc, off);
            if (lane >= off) sc += up;
        }
        if (lane == 63) wsum[wv] = sc;                  // wave totals
        __syncthreads();
        if (wv == 0 && lane < 8) {                      // exclusive scan of 8
            const int v0 = wsum[lane];
            int s = v0;
#pragma unroll
            for (int off = 1; off < 8; off <<= 1) {
                const int up = __shfl_up(s, off);
                if (lane >= off) s += up;
            }
            wsum[lane] = s - v0;
        }
        __syncthreads();
        const int run = wsum[wv] + (sc - tot);          // global exclusive prefix
        hcur[2 * t]     = run;
        hcur[2 * t + 1] = run + l0;
        __syncthreads();
        for (int v = base + t; v < end; v += 512) {     // place sorted in LDS
            const int s = sp[v];
            const int b = s >> 5, sl = s & 31;
            const int pos = atomicAdd(&hcur[b], 1);
            rec[pos] = make_uint2((unsigned)ht[v] | ((unsigned)sl << HT_BITS),
                                  __float_as_uint(w[v]));
        }
        __syncthreads();
        // dump: fully sequential, coalesced; hcur[b] is now bucket b's END.
        for (int i = t; i < n; i += 512)
            records[(size_t)blk * CHUNK + i] = rec[i];
        blkcur[(size_t)blk * NBUCKET + 2 * t]     = hcur[2 * t];
        blkcur[(size_t)blk * NBUCKET + 2 * t + 1] = hcur[2 * t + 1];
    } else {
        // ---------------- transpose role ----------------
        float* tile = (float*)smem;                     // [64][129] 33 KB
        const int ht0 = ((int)blockIdx.x - nrb) * 64;
        for (int e = t; e < 128 * 16; e += 512) {       // float4 loads
            const int ch = e >> 4, hq = e & 15;
            const float4 v = *(const float4*)(x + (size_t)ch * HW + ht0 + 4 * hq);
            const int a = 4 * hq;
            tile[(a + 0) * 129 + ch] = v.x;
            tile[(a + 1) * 129 + ch] = v.y;
            tile[(a + 2) * 129 + ch] = v.z;
            tile[(a + 3) * 129 + ch] = v.w;
        }
        __syncthreads();
        for (int e = t; e < 64 * 32; e += 512) {        // uint2 stores
            const int hl = e >> 5, cp = (e & 31) * 2;
            const unsigned lo0 = bf16_rne(tile[hl * 129 + cp]);
            const unsigned hi0 = bf16_rne(tile[hl * 129 + cp + 64]);
            const unsigned lo1 = bf16_rne(tile[hl * 129 + cp + 1]);
            const unsigned hi1 = bf16_rne(tile[hl * 129 + cp + 65]);
            *(uint2*)(xTb + (size_t)(ht0 + hl) * 64 + cp) =
                make_uint2(lo0 | (hi0 << 16), lo1 | (hi1 << 16));
        }
    }
}

// One block per bucket, 8 waves x 64 lanes. Stage: all 512 threads copy
// record i (segment found by 8-step LDS binsearch over segpos; consecutive
// i -> same segment -> coalesced reads), then fine-sort into 32 bins.
// Gather: wave owns 4 bins, processed one at a time with 8 register
// accumulators; QUARTER-WAVE processes one vote (lane ql loads dwordx4 =
// channels {4ql..4ql+3, 4ql+64..4ql+67}); loop is clamp-padded
// (kc=min(kk,s1-1), wt=0 pad) so loads are unconditional -> unroll 2 gives
// 8 gathers in flight. Quarters combined via shfl_xor(16)+(32); lanes 0..15
// write the bin's epi row right after its reduce (epi rows wave-disjoint;
// rawbuf is dead after fine-sort). Epilogue out-stores are NONTEMPORAL
// (write-once, never re-read; keep L2 for the gather table).
__global__ __launch_bounds__(512) void accum_kernel(
    const uint32_t* __restrict__ xTb, const uint2* __restrict__ records,
    const int* __restrict__ blkcur, int nrb, float* __restrict__ out) {
    __shared__ uint2 sorted[CAP];                        // 16 KB
    __shared__ __align__(16) char rawbuf[BINS * 129 * 4];// 16.5 KB raw/epilogue
    __shared__ int hist[BINS], off[BINS + 1], cur[BINS];
    __shared__ int segcnt[MAXRB], segpos[MAXRB], segs0[MAXRB];
    __shared__ int ntot;
    uint2* raw = (uint2*)rawbuf;
    float* epi = (float*)rawbuf;                         // [32][129] after sort
    const uint4* xTb4 = (const uint4*)xTb;               // [HW][16] uint4 rows
    const int bkt = blockIdx.x, t = threadIdx.x;
    const int lane = t & 63, wv = t >> 6;                // 8 waves
    const int q = lane >> 4, ql = lane & 15;             // quarter-wave id/lane

    if (t < BINS) hist[t] = 0;
    // segment boundaries for this bucket in each block's sorted chunk
    if (t < nrb) {
        const int e1 = blkcur[(size_t)t * NBUCKET + bkt];
        const int s0 = (bkt == 0) ? 0 : blkcur[(size_t)t * NBUCKET + bkt - 1];
        segcnt[t] = e1 - s0;
        segs0[t]  = s0;
    }
    __syncthreads();
    if (wv == 0) {                                       // scan nrb counts
        int carry = 0;
        for (int b0 = 0; b0 < nrb; b0 += 64) {
            const int idx = b0 + lane;
            const int c = (idx < nrb) ? segcnt[idx] : 0;
            int sc = c;
#pragma unroll
            for (int off2 = 1; off2 < 64; off2 <<= 1) {
                const int up = __shfl_up(sc, off2);
                if (lane >= off2) sc += up;
            }
            if (idx < nrb) segpos[idx] = carry + sc - c; // exclusive
            carry += __shfl(sc, 63);
        }
        if (lane == 0) ntot = carry;
    }
    __syncthreads();
    const int n = min(ntot, CAP);                        // CAP = +15 sigma guard
    // all-thread staging: 8-step binsearch for segment of record i
    for (int i = t; i < n; i += 512) {
        int lo = 0, hi = nrb - 1;
#pragma unroll
        for (int it = 0; it < 8; ++it) {                 // 2^8 >= MAXRB
            const int mid = (lo + hi + 1) >> 1;
            if (segpos[mid] <= i) lo = mid; else hi = mid - 1;
        }
        const uint2 r = records[(size_t)lo * CHUNK + segs0[lo] + (i - segpos[lo])];
        raw[i] = r;
        atomicAdd(&hist[(r.x >> HT_BITS) & 31], 1);
    }
    __syncthreads();
    if (t == 0) {                                        // tiny 32-entry scan
        int run = 0;
        for (int j = 0; j < BINS; ++j) { off[j] = run; cur[j] = run; run += hist[j]; }
        off[BINS] = run;
    }
    __syncthreads();
    for (int i = t; i < n; i += 512) {                   // place fine-sorted
        const uint2 r = raw[i];
        const int pos = atomicAdd(&cur[(r.x >> HT_BITS) & 31], 1);
        sorted[pos] = r;
    }
    __syncthreads();                                     // rawbuf now dead -> epi
#pragma unroll 1
    for (int bb = 0; bb < 4; ++bb) {                     // wave-uniform control
        const int f = wv * 4 + bb;
        const int s0f = off[f], s1f = off[f + 1];
        float a0 = 0.f, a1 = 0.f, a2 = 0.f, a3 = 0.f;
        float a4 = 0.f, a5 = 0.f, a6 = 0.f, a7 = 0.f;
#pragma unroll 2
        for (int k = s0f; k < s1f; k += 16) {            // 4 votes/wave/iter
#pragma unroll
            for (int u = 0; u < 4; ++u) {
                const int kk = k + 4 * u + q;
                const int kc = min(kk, s1f - 1);         // clamp: loads uncond.
                const uint2 r = sorted[kc];              // 4-addr LDS broadcast
                const uint4 g = xTb4[(size_t)(r.x & 0x3FFFF) * 16 + ql];
                const float wt = (kk < s1f) ? __uint_as_float(r.y) : 0.f;
                a0 += __uint_as_float(g.x << 16)          * wt;
                a1 += __uint_as_float(g.x & 0xFFFF0000u)  * wt;
                a2 += __uint_as_float(g.y << 16)          * wt;
                a3 += __uint_as_float(g.y & 0xFFFF0000u)  * wt;
                a4 += __uint_as_float(g.z << 16)          * wt;
                a5 += __uint_as_float(g.z & 0xFFFF0000u)  * wt;
                a6 += __uint_as_float(g.w << 16)          * wt;
                a7 += __uint_as_float(g.w & 0xFFFF0000u)  * wt;
            }
        }
        // combine quarter-waves in registers: lane^16 then lane^32 (race-free)
        a0 += __shfl_xor(a0, 16); a0 += __shfl_xor(a0, 32);
        a1 += __shfl_xor(a1, 16); a1 += __shfl_xor(a1, 32);
        a2 += __shfl_xor(a2, 16); a2 += __shfl_xor(a2, 32);
        a3 += __shfl_xor(a3, 16); a3 += __shfl_xor(a3, 32);
        a4 += __shfl_xor(a4, 16); a4 += __shfl_xor(a4, 32);
        a5 += __shfl_xor(a5, 16); a5 += __shfl_xor(a5, 32);
        a6 += __shfl_xor(a6, 16); a6 += __shfl_xor(a6, 32);
        a7 += __shfl_xor(a7, 16); a7 += __shfl_xor(a7, 32);
        // write this bin's epi row now (rows are wave-disjoint: f = wv*4+bb)
        if (lane < 16) {
            epi[f * 129 + 4 * ql]      = a0;
            epi[f * 129 + 4 * ql + 64] = a1;
            epi[f * 129 + 4 * ql + 1]  = a2;
            epi[f * 129 + 4 * ql + 65] = a3;
            epi[f * 129 + 4 * ql + 2]  = a4;
            epi[f * 129 + 4 * ql + 66] = a5;
            epi[f * 129 + 4 * ql + 3]  = a6;
            epi[f * 129 + 4 * ql + 67] = a7;
        }
    }
    __syncthreads();
    for (int i = t; i < 128 * BINS; i += 512) {
        const int ch = i >> 5, bin = i & 31;
        __builtin_nontemporal_store(epi[bin * 129 + ch],
                                    &out[(size_t)ch * S_BINS + bkt * BINS + bin]);
    }
}

// ---- fallback (direct atomic, any shape) ----
__global__ void direct_kernel(const float* __restrict__ x,
                              const int* __restrict__ ht_idx,
                              const int* __restrict__ sp_idx,
                              const float* __restrict__ weight,
                              float* __restrict__ out, int V, int HW, int S,
                              int CH) {
    const int v = blockIdx.x * 2 + (threadIdx.x >> 7);
    if (v >= V) return;
    const int ch = threadIdx.x & 127;
    if (ch >= CH) return;
    atomicAdd(&out[(size_t)ch * S + sp_idx[v]],
              x[(size_t)ch * HW + ht_idx[v]] * weight[v]);
}

extern "C" void kernel_launch(void* const* d_in, const int* in_sizes, int n_in,
                              void* d_out, int out_size, void* d_ws, size_t ws_size,
                              hipStream_t stream) {
    const float* x  = (const float*)d_in[0];
    const int*   ht = (const int*)d_in[1];
    const int*   sp = (const int*)d_in[2];
    const float* w  = (const float*)d_in[3];
    float* out = (float*)d_out;

    const int HW = 512 * 512;
    const int CH = in_sizes[0] / HW;          // 128
    const int S  = out_size / CH;             // 32768
    const int V  = in_sizes[1];               // 1.5M
    const int nrb = (V + CHUNK - 1) / CHUNK;  // 184 reorder-role blocks
    const int ntb = HW / 64;                  // 4096 transpose-role blocks

    const size_t xTb_bytes = (size_t)CH * HW * sizeof(uint16_t);      // 64 MB
    const size_t rec_bytes = (size_t)MAXRB * CHUNK * sizeof(uint2);   // 12.6 MB
    const size_t cur_bytes = (size_t)MAXRB * NBUCKET * sizeof(int);   // 0.79 MB
    const size_t need = xTb_bytes + rec_bytes + cur_bytes;

    if (CH == 128 && S == S_BINS && HW == (1 << HT_BITS) && nrb <= MAXRB &&
        ws_size >= need) {
        char* p = (char*)d_ws;
        uint32_t* xTb  = (uint32_t*)p;  p += xTb_bytes;
        uint2* records = (uint2*)p;     p += rec_bytes;
        int* blkcur    = (int*)p;

        fused_tr_kernel<<<nrb + ntb, 512, 0, stream>>>(
            x, xTb, HW, ht, sp, w, records, blkcur, V, nrb);
        accum_kernel<<<NBUCKET, 512, 0, stream>>>(xTb, records, blkcur, nrb,
                                                  out);
    } else {
        hipMemsetAsync(out, 0, (size_t)out_size * sizeof(float), stream);
        direct_kernel<<<(V + 1) / 2, 256, 0, stream>>>(x, ht, sp, w, out, V, HW,
                                                       S, CH);
    }
}